// Round 14
// baseline (3293.330 us; speedup 1.0000x reference)
//
#include <hip/hip_runtime.h>

// DependencyParser: 2× two-layer BiLSTM (word E=512, pos P=128), T=1024, B=1,
// then rank-1 edge scores S[i][j] = H[i]@w1 + H[j]@w2 + b, diag=0.
//
// R14 = R13 (total 3249us; rec-0 1627 w/ fused df-GEMM, rec-1 1572) + cleanup:
//  - df/gemm LDS tiles padded [16][68]: write conflicts 4-way -> 2-way (free).
//  - edge scores fused into rec-1 launch as 16 sentinel-df WGs (row block
//    [64r,64r+64) ready when hw1_f row 64r+63 / hw1_b row 64r / hp1 analogs
//    are non-poison). edge_s dispatch removed; hp1_* poisoned.
//  - rec_kernel gains a mode flag: 0 = xg1 dataflow GEMM WGs (rec-0 launch),
//    1 = edge dataflow WGs (rec-1 launch).
// Exchange protocol + word/pos bodies unchanged (protocol floor per
// R6/R10/R11/R12 null results).

#define T_LEN 1024

// ---------------------------------------------------------------- poison ----
__global__ void poison_kernel(unsigned* p, int n) {
  int i = blockIdx.x * blockDim.x + threadIdx.x;
  int stride = gridDim.x * blockDim.x;
  for (; i < n; i += stride) p[i] = 0xFFFFFFFFu;
}

// ------------------------------------------------ GEMM C = A@W^T + b0 + b1 ----
// A: [M][K], W: [2][N][K] (z = direction), C: [2][M][N]. 64x64 tile, 256 thr.
__global__ __launch_bounds__(256) void gemm_bt(
    const float* __restrict__ A,
    const float* __restrict__ Wt,
    const float* __restrict__ B0,
    const float* __restrict__ B1,
    float* __restrict__ C,
    int M, int N, int K)
{
  const int z = blockIdx.z;
  const float* W  = Wt + (size_t)z * N * K;
  const float* b0 = B0 + (size_t)z * N;
  const float* b1 = B1 + (size_t)z * N;
  float* Cz = C + (size_t)z * M * N;

  __shared__ __align__(16) float As[16][68];
  __shared__ __align__(16) float Ws[16][68];

  const int tid = threadIdx.x;
  const int tx = tid & 15, ty = tid >> 4;
  const int brow = blockIdx.y * 64, bcol = blockIdx.x * 64;
  const int lr = tid >> 2;          // 0..63
  const int lk = (tid & 3) << 2;    // 0,4,8,12

  float acc[4][4] = {};

  for (int k0 = 0; k0 < K; k0 += 16) {
    float4 av = *(const float4*)(A + (size_t)(brow + lr) * K + k0 + lk);
    float4 wv = *(const float4*)(W + (size_t)(bcol + lr) * K + k0 + lk);
    __syncthreads();
    As[lk + 0][lr] = av.x; As[lk + 1][lr] = av.y;
    As[lk + 2][lr] = av.z; As[lk + 3][lr] = av.w;
    Ws[lk + 0][lr] = wv.x; Ws[lk + 1][lr] = wv.y;
    Ws[lk + 2][lr] = wv.z; Ws[lk + 3][lr] = wv.w;
    __syncthreads();
    #pragma unroll
    for (int kk = 0; kk < 16; ++kk) {
      float4 a = *(const float4*)&As[kk][ty << 2];
      float4 w = *(const float4*)&Ws[kk][tx << 2];
      float a4[4] = {a.x, a.y, a.z, a.w};
      float w4[4] = {w.x, w.y, w.z, w.w};
      #pragma unroll
      for (int i = 0; i < 4; ++i)
        #pragma unroll
        for (int j = 0; j < 4; ++j)
          acc[i][j] = fmaf(a4[i], w4[j], acc[i][j]);
    }
  }

  const int nb = bcol + (tx << 2);
  float bias[4];
  #pragma unroll
  for (int j = 0; j < 4; ++j) bias[j] = b0[nb + j] + b1[nb + j];
  #pragma unroll
  for (int i = 0; i < 4; ++i) {
    int m = brow + (ty << 2) + i;
    float4 out;
    out.x = acc[i][0] + bias[0];
    out.y = acc[i][1] + bias[1];
    out.z = acc[i][2] + bias[2];
    out.w = acc[i][3] + bias[3];
    *(float4*)(Cz + (size_t)m * N + nb) = out;
  }
}

// --------------------------------------------------------- fast activations ----
__device__ __forceinline__ float fsigmoid(float x) {
  return 1.f / (1.f + __expf(-x));
}
__device__ __forceinline__ float ftanh(float x) {
  return 2.f / (1.f + __expf(-2.f * x)) - 1.f;
}

// DPP add: v += dpp(v). 0xB1 xor1, 0x4E xor2, 0x141 row_half_mirror,
// 0x140 row_mirror, 0x142 row_bcast15 (32-lane total lands on p>=16).
template<int CTRL>
__device__ __forceinline__ float dpp_add(float v) {
  int x = __builtin_amdgcn_update_dpp(0, __float_as_int(v), CTRL, 0xf, 0xf, true);
  return v + __int_as_float(x);
}

// ---------------------------------------- word LSTM (R12, unchanged) ----
__device__ __forceinline__ void word_body(
    int wg, const float* __restrict__ xg, const float* __restrict__ whh,
    float* hbuf, int rev)
{
  const int tid  = threadIdx.x;
  const int wave = tid >> 6;
  const int lane = tid & 63;
  const int p    = lane & 31;
  const int half = lane >> 5;
  const int eloc = wave * 2 + half;      // 0..15
  const int e    = wg * 16 + eloc;       // global h element 0..511

  float4 wv[4][4];
  #pragma unroll
  for (int g = 0; g < 4; ++g) {
    const float* row = whh + (size_t)(g * 512 + e) * 512 + 4 * p;
    #pragma unroll
    for (int k = 0; k < 4; ++k)
      wv[g][k] = *(const float4*)(row + 128 * k);
  }

  __shared__ __align__(16) float h_lds[512];
  __shared__ __align__(16) float4 hgates[16];

  unsigned* hb = (unsigned*)hbuf;

  const bool tail = (tid < 16);
  float cst = 0.f;
  float xg4[4] = {0.f, 0.f, 0.f, 0.f};
  if (tail) {
    const int t0 = rev ? (T_LEN - 1) : 0;
    #pragma unroll
    for (int g = 0; g < 4; ++g)
      xg4[g] = xg[(size_t)t0 * 2048 + g * 512 + wg * 16 + tid];
  }

  unsigned A = 0, B = 0, C = 0;

  for (int s = 0; s < T_LEN; ++s) {
    const int t = rev ? (T_LEN - 1 - s) : s;

    if (s == 0) {
      h_lds[tid] = 0.f;
    } else {
      const int tp = rev ? (t + 1) : (t - 1);
      const unsigned* addr = hb + (size_t)tp * 512 + tid;
      asm volatile(
          "s_waitcnt vmcnt(0)\n\t"
          "global_load_dword %0, %3, off sc0 sc1\n\t"
          "global_load_dword %1, %3, off sc0 sc1\n\t"
          "global_load_dword %2, %3, off sc0 sc1\n\t"
          "Lpoll%=:\n\t"
          "s_waitcnt vmcnt(2)\n\t"
          "v_cmp_eq_u32 vcc, -1, %0\n\t"
          "s_cbranch_vccz Ldone%=\n\t"
          "global_load_dword %0, %3, off sc0 sc1\n\t"
          "s_waitcnt vmcnt(2)\n\t"
          "v_cmp_eq_u32 vcc, -1, %1\n\t"
          "s_cbranch_vccz LuseB%=\n\t"
          "global_load_dword %1, %3, off sc0 sc1\n\t"
          "s_waitcnt vmcnt(2)\n\t"
          "v_cmp_eq_u32 vcc, -1, %2\n\t"
          "s_cbranch_vccz LuseC%=\n\t"
          "global_load_dword %2, %3, off sc0 sc1\n\t"
          "s_branch Lpoll%=\n\t"
          "LuseB%=:\n\t"
          "v_mov_b32 %0, %1\n\t"
          "s_branch Ldone%=\n\t"
          "LuseC%=:\n\t"
          "v_mov_b32 %0, %2\n\t"
          "Ldone%=:"
          : "+v"(A), "+v"(B), "+v"(C)
          : "v"(addr)
          : "vcc", "memory");
      h_lds[tid] = __uint_as_float(A);
    }
    __syncthreads();   // B1

    float a0 = 0.f, a1 = 0.f, a2 = 0.f, a3 = 0.f;
    #pragma unroll
    for (int k = 0; k < 4; ++k) {
      float4 hv = *(const float4*)&h_lds[128 * k + 4 * p];
      float h4[4] = {hv.x, hv.y, hv.z, hv.w};
      #pragma unroll
      for (int j = 0; j < 4; ++j) {
        a0 = fmaf(((const float*)&wv[0][k])[j], h4[j], a0);
        a1 = fmaf(((const float*)&wv[1][k])[j], h4[j], a1);
        a2 = fmaf(((const float*)&wv[2][k])[j], h4[j], a2);
        a3 = fmaf(((const float*)&wv[3][k])[j], h4[j], a3);
      }
    }

    a0 = dpp_add<0xB1>(a0);  a1 = dpp_add<0xB1>(a1);
    a2 = dpp_add<0xB1>(a2);  a3 = dpp_add<0xB1>(a3);
    a0 = dpp_add<0x4E>(a0);  a1 = dpp_add<0x4E>(a1);
    a2 = dpp_add<0x4E>(a2);  a3 = dpp_add<0x4E>(a3);
    a0 = dpp_add<0x141>(a0); a1 = dpp_add<0x141>(a1);
    a2 = dpp_add<0x141>(a2); a3 = dpp_add<0x141>(a3);
    a0 = dpp_add<0x140>(a0); a1 = dpp_add<0x140>(a1);
    a2 = dpp_add<0x140>(a2); a3 = dpp_add<0x140>(a3);
    a0 = dpp_add<0x142>(a0); a1 = dpp_add<0x142>(a1);
    a2 = dpp_add<0x142>(a2); a3 = dpp_add<0x142>(a3);

    if (p == 16) {
      float4 gsum; gsum.x = a0; gsum.y = a1; gsum.z = a2; gsum.w = a3;
      hgates[eloc] = gsum;
    }
    __syncthreads();   // B2

    if (tail) {
      float4 g4 = hgates[tid];
      float si = fsigmoid(g4.x + xg4[0]);
      float sf = fsigmoid(g4.y + xg4[1]);
      float tg = ftanh  (g4.z + xg4[2]);
      float so = fsigmoid(g4.w + xg4[3]);
      cst = fmaf(sf, cst, si * tg);
      float h = so * ftanh(cst);
      __hip_atomic_store(hb + (size_t)t * 512 + wg * 16 + tid,
                         __float_as_uint(h),
                         __ATOMIC_RELAXED, __HIP_MEMORY_SCOPE_AGENT);
      if (s + 1 < T_LEN) {
        const int tn = rev ? (t - 1) : (t + 1);
        #pragma unroll
        for (int g = 0; g < 4; ++g)
          xg4[g] = xg[(size_t)tn * 2048 + g * 512 + wg * 16 + tid];
      }
    }
  }

  asm volatile("s_waitcnt vmcnt(0)" : "+v"(A), "+v"(B), "+v"(C) :: "memory");
}

// --------------------------------- pos LSTM (agent-scope history stores) ----
__device__ __forceinline__ void pos_body(
    const float* __restrict__ xg, const float* __restrict__ whh,
    float* __restrict__ hbuf, int rev)
{
  const int tid = threadIdx.x;
  const int p   = tid & 3;
  const int e   = tid >> 2;        // 0..127

  float w[4][32];
  #pragma unroll
  for (int g = 0; g < 4; ++g) {
    const float* row = whh + (size_t)(g * 128 + e) * 128 + 4 * p;
    #pragma unroll
    for (int k = 0; k < 8; ++k) {
      float4 v = *(const float4*)(row + 16 * k);
      w[g][k * 4 + 0] = v.x; w[g][k * 4 + 1] = v.y;
      w[g][k * 4 + 2] = v.z; w[g][k * 4 + 3] = v.w;
    }
  }

  __shared__ __align__(16) float h_lds[2][128];
  unsigned* hb = (unsigned*)hbuf;

  float cst = 0.f;
  float xg4[4] = {0.f, 0.f, 0.f, 0.f};
  if (p == 0) {
    const int t0 = rev ? (T_LEN - 1) : 0;
    #pragma unroll
    for (int g = 0; g < 4; ++g) xg4[g] = xg[(size_t)t0 * 512 + g * 128 + e];
  }
  if (tid < 128) h_lds[0][tid] = 0.f;
  __syncthreads();

  for (int s = 0; s < T_LEN; ++s) {
    const int t   = rev ? (T_LEN - 1 - s) : s;
    const int buf = s & 1;

    float a0 = 0.f, a1 = 0.f, a2 = 0.f, a3 = 0.f;
    #pragma unroll
    for (int k = 0; k < 8; ++k) {
      float4 hv = *(const float4*)&h_lds[buf][16 * k + 4 * p];
      float h4[4] = {hv.x, hv.y, hv.z, hv.w};
      #pragma unroll
      for (int j = 0; j < 4; ++j) {
        a0 = fmaf(w[0][k * 4 + j], h4[j], a0);
        a1 = fmaf(w[1][k * 4 + j], h4[j], a1);
        a2 = fmaf(w[2][k * 4 + j], h4[j], a2);
        a3 = fmaf(w[3][k * 4 + j], h4[j], a3);
      }
    }
    a0 = dpp_add<0xB1>(a0); a1 = dpp_add<0xB1>(a1);
    a2 = dpp_add<0xB1>(a2); a3 = dpp_add<0xB1>(a3);
    a0 = dpp_add<0x4E>(a0); a1 = dpp_add<0x4E>(a1);
    a2 = dpp_add<0x4E>(a2); a3 = dpp_add<0x4E>(a3);

    if (p == 0) {
      float si = fsigmoid(a0 + xg4[0]);
      float sf = fsigmoid(a1 + xg4[1]);
      float tg = ftanh  (a2 + xg4[2]);
      float so = fsigmoid(a3 + xg4[3]);
      cst = fmaf(sf, cst, si * tg);
      float h = so * ftanh(cst);
      h_lds[buf ^ 1][e] = h;                 // next step's operand
      __hip_atomic_store(hb + (size_t)t * 128 + e, __float_as_uint(h),
                         __ATOMIC_RELAXED, __HIP_MEMORY_SCOPE_AGENT);
      if (s + 1 < T_LEN) {
        const int tn = rev ? (t - 1) : (t + 1);
        #pragma unroll
        for (int g = 0; g < 4; ++g)
          xg4[g] = xg[(size_t)tn * 512 + g * 128 + e];
      }
    }
    __syncthreads();
  }
}

// --------------------------------------------- dataflow layer-1 GEMM tile ----
// Readiness order for 64-row tiles: ready step = max(64b+63, 1023-64b).
__device__ const int rtorder[16] = {7,8,6,9,5,10,4,11,3,12,2,13,1,14,0,15};

// Wait until sentinel rows are fully published (agent loads; FF = not ready).
__device__ __forceinline__ void wait_rows(const unsigned* rowF,
                                          const unsigned* rowB, int width) {
  const int tid = threadIdx.x;
  if (tid < width) {
    while (__hip_atomic_load(rowF + tid, __ATOMIC_RELAXED,
                             __HIP_MEMORY_SCOPE_AGENT) == 0xFFFFFFFFu)
      __builtin_amdgcn_s_sleep(8);
    while (__hip_atomic_load(rowB + tid, __ATOMIC_RELAXED,
                             __HIP_MEMORY_SCOPE_AGENT) == 0xFFFFFFFFu)
      __builtin_amdgcn_s_sleep(8);
  }
  __syncthreads();
}

// 64x64 tile of C = [Alo|Ahi] @ W^T + b0 + b1 (K split at ksplit).
// 512 threads launched; tid<256 compute, all hit the barriers.
__device__ __forceinline__ void df_tile(
    const float* __restrict__ Alo, const float* __restrict__ Ahi, int ksplit,
    int K, const float* __restrict__ W,
    const float* __restrict__ b0, const float* __restrict__ b1,
    float* __restrict__ C, int N, int brow, int bcol)
{
  __shared__ __align__(16) float As[16][68];
  __shared__ __align__(16) float Ws[16][68];

  const int tid = threadIdx.x;
  const int tx = tid & 15, ty = (tid >> 4) & 15;
  const int lr = (tid >> 2) & 63;
  const int lk = (tid & 3) << 2;

  float acc[4][4] = {};

  for (int k0 = 0; k0 < K; k0 += 16) {
    float4 av, wv;
    if (tid < 256) {
      const int k = k0 + lk;
      const float* arow = (k < ksplit)
          ? (Alo + (size_t)(brow + lr) * ksplit + k)
          : (Ahi + (size_t)(brow + lr) * ksplit + (k - ksplit));
      av = *(const float4*)arow;
      wv = *(const float4*)(W + (size_t)(bcol + lr) * K + k0 + lk);
    }
    __syncthreads();
    if (tid < 256) {
      As[lk + 0][lr] = av.x; As[lk + 1][lr] = av.y;
      As[lk + 2][lr] = av.z; As[lk + 3][lr] = av.w;
      Ws[lk + 0][lr] = wv.x; Ws[lk + 1][lr] = wv.y;
      Ws[lk + 2][lr] = wv.z; Ws[lk + 3][lr] = wv.w;
    }
    __syncthreads();
    if (tid < 256) {
      #pragma unroll
      for (int kk = 0; kk < 16; ++kk) {
        float4 a = *(const float4*)&As[kk][ty << 2];
        float4 w = *(const float4*)&Ws[kk][tx << 2];
        float a4[4] = {a.x, a.y, a.z, a.w};
        float w4[4] = {w.x, w.y, w.z, w.w};
        #pragma unroll
        for (int i = 0; i < 4; ++i)
          #pragma unroll
          for (int j = 0; j < 4; ++j)
            acc[i][j] = fmaf(a4[i], w4[j], acc[i][j]);
      }
    }
  }

  if (tid < 256) {
    const int nb = bcol + (tx << 2);
    float bias[4];
    #pragma unroll
    for (int j = 0; j < 4; ++j) bias[j] = b0[nb + j] + b1[nb + j];
    #pragma unroll
    for (int i = 0; i < 4; ++i) {
      int m = brow + (ty << 2) + i;
      float4 out;
      out.x = acc[i][0] + bias[0];
      out.y = acc[i][1] + bias[1];
      out.z = acc[i][2] + bias[2];
      out.w = acc[i][3] + bias[3];
      *(float4*)(C + (size_t)m * N + nb) = out;
    }
  }
}

// ------------------------------------------------- dataflow edge row block ----
// s1[i] = H[i]@ew[0:1280], s2[i] = H[i]@ew[1280:2560] for i in [64r, 64r+64).
__device__ __forceinline__ void edge_block(
    int r, const float* __restrict__ hwf, const float* __restrict__ hwb,
    const float* __restrict__ hpf, const float* __restrict__ hpb,
    const float* __restrict__ ew, float* s1, float* s2)
{
  wait_rows((const unsigned*)(hwf + (size_t)(r * 64 + 63) * 512),
            (const unsigned*)(hwb + (size_t)(r * 64) * 512), 512);
  wait_rows((const unsigned*)(hpf + (size_t)(r * 64 + 63) * 128),
            (const unsigned*)(hpb + (size_t)(r * 64) * 128), 128);
  const int tid  = threadIdx.x;
  const int wv   = tid >> 6;       // wave 0..7
  const int lane = tid & 63;
  for (int rr = wv; rr < 64; rr += 8) {
    const int i = r * 64 + rr;
    float a1 = 0.f, a2 = 0.f;
    for (int d = lane; d < 1280; d += 64) {
      float hv;
      if (d < 512)       hv = hwf[i * 512 + d];
      else if (d < 1024) hv = hwb[i * 512 + d - 512];
      else if (d < 1152) hv = hpf[i * 128 + d - 1024];
      else               hv = hpb[i * 128 + d - 1152];
      a1 = fmaf(hv, ew[d], a1);
      a2 = fmaf(hv, ew[1280 + d], a2);
    }
    #pragma unroll
    for (int off = 32; off > 0; off >>= 1) {
      a1 += __shfl_xor(a1, off, 64);
      a2 += __shfl_xor(a2, off, 64);
    }
    if (lane == 0) { s1[i] = a1; s2[i] = a2; }
  }
}

// --------------------------------------------------------- rec (combined) ----
__global__ __launch_bounds__(512, 1) void rec_kernel(
    const float* xg_wf, const float* xg_wb, const float* whh_w,
    float* h_wf, float* h_wb,
    const float* xg_pf, const float* xg_pb, const float* whh_p,
    float* h_pf, float* h_pb,
    const float* w1_ih, const float* w1_b0, const float* w1_b1, float* xg1_w,
    const float* p1_ih, const float* p1_b0, const float* p1_b1, float* xg1_p,
    const float* ew, float* s1, float* s2, int mode)
{
  const int b = blockIdx.x;
  if (b < 32) {
    word_body(b, xg_wf, whh_w, h_wf, 0);
  } else if (b < 64) {
    word_body(b - 32, xg_wb, whh_w + 2048 * 512, h_wb, 1);
  } else if (b == 64) {
    pos_body(xg_pf, whh_p, h_pf, 0);
  } else if (b == 65) {
    pos_body(xg_pb, whh_p + 512 * 128, h_pb, 1);
  } else if (mode == 0) {
    if (b < 194) {
      // word layer-1 dataflow GEMM: 1024 jobs over 128 WGs
      const int g = b - 66;
      for (int j = g; j < 1024; j += 128) {
        const int rti = rtorder[j >> 6];
        const int rem = j & 63;
        const int z = rem >> 5, ct = rem & 31;
        const int brow = rti * 64, bcol = ct * 64;
        wait_rows((const unsigned*)(h_wf + (size_t)(brow + 63) * 512),
                  (const unsigned*)(h_wb + (size_t)brow * 512), 512);
        df_tile(h_wf, h_wb, 512, 1024,
                w1_ih + (size_t)z * 2048 * 1024,
                w1_b0 + z * 2048, w1_b1 + z * 2048,
                xg1_w + (size_t)z * 1024 * 2048, 2048, brow, bcol);
      }
    } else {
      // pos layer-1 dataflow GEMM: 256 jobs over 8 WGs
      const int g = b - 194;
      for (int j = g; j < 256; j += 8) {
        const int rti = rtorder[j >> 4];
        const int rem = j & 15;
        const int z = rem >> 3, ct = rem & 7;
        const int brow = rti * 64, bcol = ct * 64;
        wait_rows((const unsigned*)(h_pf + (size_t)(brow + 63) * 128),
                  (const unsigned*)(h_pb + (size_t)brow * 128), 128);
        df_tile(h_pf, h_pb, 128, 256,
                p1_ih + (size_t)z * 512 * 256,
                p1_b0 + z * 512, p1_b1 + z * 512,
                xg1_p + (size_t)z * 1024 * 512, 512, brow, bcol);
      }
    }
  } else {
    // edge dataflow: blocks 66..81 -> row blocks 0..15
    edge_block(b - 66, h_wf, h_wb, h_pf, h_pb, ew, s1, s2);
  }
}

// ------------------------------------------------------------------ sfill ----
__global__ __launch_bounds__(256) void sfill(
    const float* __restrict__ s1, const float* __restrict__ s2,
    const float* __restrict__ eb, float* __restrict__ out)
{
  int e = blockIdx.x * 256 + threadIdx.x;  // 0 .. 1024*1024-1
  int i = e >> 10, j = e & 1023;
  out[e] = (i == j) ? 0.f : s1[i] + s2[j] + eb[0];
}

// ------------------------------------------------------------------ launch ----
extern "C" void kernel_launch(void* const* d_in, const int* in_sizes, int n_in,
                              void* d_out, int out_size, void* d_ws, size_t ws_size,
                              hipStream_t stream)
{
  const float* words   = (const float*)d_in[0];
  const float* pos     = (const float*)d_in[1];
  const float* w_w0_ih = (const float*)d_in[2];
  const float* w_w0_hh = (const float*)d_in[3];
  const float* w_b0_ih = (const float*)d_in[4];
  const float* w_b0_hh = (const float*)d_in[5];
  const float* w_w1_ih = (const float*)d_in[6];
  const float* w_w1_hh = (const float*)d_in[7];
  const float* w_b1_ih = (const float*)d_in[8];
  const float* w_b1_hh = (const float*)d_in[9];
  const float* p_w0_ih = (const float*)d_in[10];
  const float* p_w0_hh = (const float*)d_in[11];
  const float* p_b0_ih = (const float*)d_in[12];
  const float* p_b0_hh = (const float*)d_in[13];
  const float* p_w1_ih = (const float*)d_in[14];
  const float* p_w1_hh = (const float*)d_in[15];
  const float* p_b1_ih = (const float*)d_in[16];
  const float* p_b1_hh = (const float*)d_in[17];
  const float* edge_w  = (const float*)d_in[18];
  const float* edge_b  = (const float*)d_in[19];

  float* ws = (float*)d_ws;
  float* xg_w  = ws;                       // [2][1024][2048] (layer0, then layer1 in place)
  float* xg_p  = ws + 4194304;             // [2][1024][512]
  float* hw0_f = ws + 5242880;             // [1024][512] each (poisoned)
  float* hw0_b = hw0_f + 524288;
  float* hw1_f = hw0_b + 524288;
  float* hw1_b = hw1_f + 524288;
  float* hp0_f = hw1_b + 524288;           // [1024][128] each (poisoned)
  float* hp0_b = hp0_f + 131072;
  float* hp1_f = hp0_b + 131072;
  float* hp1_b = hp1_f + 131072;
  float* s1    = hp1_b + 131072;
  float* s2    = s1 + 1024;

  // 1. poison hw0_f..hp1_b (word exchange x4 + pos sentinels x4);
  //    every call, since the harness does not re-poison between replays.
  poison_kernel<<<1024, 256, 0, stream>>>((unsigned*)hw0_f, 2621440);

  // 2. layer-0 input projections
  gemm_bt<<<dim3(32, 16, 2), 256, 0, stream>>>(words, w_w0_ih, w_b0_ih, w_b0_hh,
                                               xg_w, 1024, 2048, 512);
  gemm_bt<<<dim3(8, 16, 2), 256, 0, stream>>>(pos, p_w0_ih, p_b0_ih, p_b0_hh,
                                              xg_p, 1024, 512, 128);

  // 3. layer-0 recurrence + dataflow layer-1 projections (202 WGs)
  rec_kernel<<<202, 512, 0, stream>>>(
      xg_w, xg_w + 2097152, w_w0_hh, hw0_f, hw0_b,
      xg_p, xg_p + 524288, p_w0_hh, hp0_f, hp0_b,
      w_w1_ih, w_b1_ih, w_b1_hh, xg_w,
      p_w1_ih, p_b1_ih, p_b1_hh, xg_p,
      edge_w, s1, s2, 0);

  // 4. layer-1 recurrence + dataflow edge scores (82 WGs)
  rec_kernel<<<82, 512, 0, stream>>>(
      xg_w, xg_w + 2097152, w_w1_hh, hw1_f, hw1_b,
      xg_p, xg_p + 524288, p_w1_hh, hp1_f, hp1_b,
      w_w1_ih, w_b1_ih, w_b1_hh, xg_w,
      p_w1_ih, p_b1_ih, p_b1_hh, xg_p,
      edge_w, s1, s2, 1);

  // 5. S fill
  sfill<<<4096, 256, 0, stream>>>(s1, s2, edge_b, (float*)d_out);
}

// Round 15
// 3242.728 us; speedup vs baseline: 1.0156x; 1.0156x over previous
//
#include <hip/hip_runtime.h>

// DependencyParser: 2× two-layer BiLSTM (word E=512, pos P=128), T=1024, B=1,
// then rank-1 edge scores S[i][j] = H[i]@w1 + H[j]@w2 + b, diag=0.
//
// R15 = best-of(R13, R14):
//  - R13 structure: dataflow layer-1 GEMM fused into rec-0 (136 sentinel
//    WGs, concat eliminated, xg overwritten in place); separate edge_s
//    dispatch after rec-1 (R14's edge-fusion cost rec-1 +55us -> dropped).
//  - R14's [16][68]-padded LDS tiles in gemm_bt/df_tile (bank conflicts
//    1.34e7 -> 4.5e6).
// Exchange protocol at its measured floor (~1.53us/step): placement (R6),
// poll sampling (R10/R12), barrier structure (R11), publish shape (R8/R9),
// and compute schedule (R2/R3/R5) all explored to null or regression.

#define T_LEN 1024

// ---------------------------------------------------------------- poison ----
__global__ void poison_kernel(unsigned* p, int n) {
  int i = blockIdx.x * blockDim.x + threadIdx.x;
  int stride = gridDim.x * blockDim.x;
  for (; i < n; i += stride) p[i] = 0xFFFFFFFFu;
}

// ------------------------------------------------ GEMM C = A@W^T + b0 + b1 ----
// A: [M][K], W: [2][N][K] (z = direction), C: [2][M][N]. 64x64 tile, 256 thr.
__global__ __launch_bounds__(256) void gemm_bt(
    const float* __restrict__ A,
    const float* __restrict__ Wt,
    const float* __restrict__ B0,
    const float* __restrict__ B1,
    float* __restrict__ C,
    int M, int N, int K)
{
  const int z = blockIdx.z;
  const float* W  = Wt + (size_t)z * N * K;
  const float* b0 = B0 + (size_t)z * N;
  const float* b1 = B1 + (size_t)z * N;
  float* Cz = C + (size_t)z * M * N;

  __shared__ __align__(16) float As[16][68];
  __shared__ __align__(16) float Ws[16][68];

  const int tid = threadIdx.x;
  const int tx = tid & 15, ty = tid >> 4;
  const int brow = blockIdx.y * 64, bcol = blockIdx.x * 64;
  const int lr = tid >> 2;          // 0..63
  const int lk = (tid & 3) << 2;    // 0,4,8,12

  float acc[4][4] = {};

  for (int k0 = 0; k0 < K; k0 += 16) {
    float4 av = *(const float4*)(A + (size_t)(brow + lr) * K + k0 + lk);
    float4 wv = *(const float4*)(W + (size_t)(bcol + lr) * K + k0 + lk);
    __syncthreads();
    As[lk + 0][lr] = av.x; As[lk + 1][lr] = av.y;
    As[lk + 2][lr] = av.z; As[lk + 3][lr] = av.w;
    Ws[lk + 0][lr] = wv.x; Ws[lk + 1][lr] = wv.y;
    Ws[lk + 2][lr] = wv.z; Ws[lk + 3][lr] = wv.w;
    __syncthreads();
    #pragma unroll
    for (int kk = 0; kk < 16; ++kk) {
      float4 a = *(const float4*)&As[kk][ty << 2];
      float4 w = *(const float4*)&Ws[kk][tx << 2];
      float a4[4] = {a.x, a.y, a.z, a.w};
      float w4[4] = {w.x, w.y, w.z, w.w};
      #pragma unroll
      for (int i = 0; i < 4; ++i)
        #pragma unroll
        for (int j = 0; j < 4; ++j)
          acc[i][j] = fmaf(a4[i], w4[j], acc[i][j]);
    }
  }

  const int nb = bcol + (tx << 2);
  float bias[4];
  #pragma unroll
  for (int j = 0; j < 4; ++j) bias[j] = b0[nb + j] + b1[nb + j];
  #pragma unroll
  for (int i = 0; i < 4; ++i) {
    int m = brow + (ty << 2) + i;
    float4 out;
    out.x = acc[i][0] + bias[0];
    out.y = acc[i][1] + bias[1];
    out.z = acc[i][2] + bias[2];
    out.w = acc[i][3] + bias[3];
    *(float4*)(Cz + (size_t)m * N + nb) = out;
  }
}

// --------------------------------------------------------- fast activations ----
__device__ __forceinline__ float fsigmoid(float x) {
  return 1.f / (1.f + __expf(-x));
}
__device__ __forceinline__ float ftanh(float x) {
  return 2.f / (1.f + __expf(-2.f * x)) - 1.f;
}

// DPP add: v += dpp(v). 0xB1 xor1, 0x4E xor2, 0x141 row_half_mirror,
// 0x140 row_mirror, 0x142 row_bcast15 (32-lane total lands on p>=16).
template<int CTRL>
__device__ __forceinline__ float dpp_add(float v) {
  int x = __builtin_amdgcn_update_dpp(0, __float_as_int(v), CTRL, 0xf, 0xf, true);
  return v + __int_as_float(x);
}

// ---------------------------------------- word LSTM (R12, unchanged) ----
__device__ __forceinline__ void word_body(
    int wg, const float* __restrict__ xg, const float* __restrict__ whh,
    float* hbuf, int rev)
{
  const int tid  = threadIdx.x;
  const int wave = tid >> 6;
  const int lane = tid & 63;
  const int p    = lane & 31;
  const int half = lane >> 5;
  const int eloc = wave * 2 + half;      // 0..15
  const int e    = wg * 16 + eloc;       // global h element 0..511

  float4 wv[4][4];
  #pragma unroll
  for (int g = 0; g < 4; ++g) {
    const float* row = whh + (size_t)(g * 512 + e) * 512 + 4 * p;
    #pragma unroll
    for (int k = 0; k < 4; ++k)
      wv[g][k] = *(const float4*)(row + 128 * k);
  }

  __shared__ __align__(16) float h_lds[512];
  __shared__ __align__(16) float4 hgates[16];

  unsigned* hb = (unsigned*)hbuf;

  const bool tail = (tid < 16);
  float cst = 0.f;
  float xg4[4] = {0.f, 0.f, 0.f, 0.f};
  if (tail) {
    const int t0 = rev ? (T_LEN - 1) : 0;
    #pragma unroll
    for (int g = 0; g < 4; ++g)
      xg4[g] = xg[(size_t)t0 * 2048 + g * 512 + wg * 16 + tid];
  }

  unsigned A = 0, B = 0, C = 0;

  for (int s = 0; s < T_LEN; ++s) {
    const int t = rev ? (T_LEN - 1 - s) : s;

    if (s == 0) {
      h_lds[tid] = 0.f;
    } else {
      const int tp = rev ? (t + 1) : (t - 1);
      const unsigned* addr = hb + (size_t)tp * 512 + tid;
      asm volatile(
          "s_waitcnt vmcnt(0)\n\t"
          "global_load_dword %0, %3, off sc0 sc1\n\t"
          "global_load_dword %1, %3, off sc0 sc1\n\t"
          "global_load_dword %2, %3, off sc0 sc1\n\t"
          "Lpoll%=:\n\t"
          "s_waitcnt vmcnt(2)\n\t"
          "v_cmp_eq_u32 vcc, -1, %0\n\t"
          "s_cbranch_vccz Ldone%=\n\t"
          "global_load_dword %0, %3, off sc0 sc1\n\t"
          "s_waitcnt vmcnt(2)\n\t"
          "v_cmp_eq_u32 vcc, -1, %1\n\t"
          "s_cbranch_vccz LuseB%=\n\t"
          "global_load_dword %1, %3, off sc0 sc1\n\t"
          "s_waitcnt vmcnt(2)\n\t"
          "v_cmp_eq_u32 vcc, -1, %2\n\t"
          "s_cbranch_vccz LuseC%=\n\t"
          "global_load_dword %2, %3, off sc0 sc1\n\t"
          "s_branch Lpoll%=\n\t"
          "LuseB%=:\n\t"
          "v_mov_b32 %0, %1\n\t"
          "s_branch Ldone%=\n\t"
          "LuseC%=:\n\t"
          "v_mov_b32 %0, %2\n\t"
          "Ldone%=:"
          : "+v"(A), "+v"(B), "+v"(C)
          : "v"(addr)
          : "vcc", "memory");
      h_lds[tid] = __uint_as_float(A);
    }
    __syncthreads();   // B1

    float a0 = 0.f, a1 = 0.f, a2 = 0.f, a3 = 0.f;
    #pragma unroll
    for (int k = 0; k < 4; ++k) {
      float4 hv = *(const float4*)&h_lds[128 * k + 4 * p];
      float h4[4] = {hv.x, hv.y, hv.z, hv.w};
      #pragma unroll
      for (int j = 0; j < 4; ++j) {
        a0 = fmaf(((const float*)&wv[0][k])[j], h4[j], a0);
        a1 = fmaf(((const float*)&wv[1][k])[j], h4[j], a1);
        a2 = fmaf(((const float*)&wv[2][k])[j], h4[j], a2);
        a3 = fmaf(((const float*)&wv[3][k])[j], h4[j], a3);
      }
    }

    a0 = dpp_add<0xB1>(a0);  a1 = dpp_add<0xB1>(a1);
    a2 = dpp_add<0xB1>(a2);  a3 = dpp_add<0xB1>(a3);
    a0 = dpp_add<0x4E>(a0);  a1 = dpp_add<0x4E>(a1);
    a2 = dpp_add<0x4E>(a2);  a3 = dpp_add<0x4E>(a3);
    a0 = dpp_add<0x141>(a0); a1 = dpp_add<0x141>(a1);
    a2 = dpp_add<0x141>(a2); a3 = dpp_add<0x141>(a3);
    a0 = dpp_add<0x140>(a0); a1 = dpp_add<0x140>(a1);
    a2 = dpp_add<0x140>(a2); a3 = dpp_add<0x140>(a3);
    a0 = dpp_add<0x142>(a0); a1 = dpp_add<0x142>(a1);
    a2 = dpp_add<0x142>(a2); a3 = dpp_add<0x142>(a3);

    if (p == 16) {
      float4 gsum; gsum.x = a0; gsum.y = a1; gsum.z = a2; gsum.w = a3;
      hgates[eloc] = gsum;
    }
    __syncthreads();   // B2

    if (tail) {
      float4 g4 = hgates[tid];
      float si = fsigmoid(g4.x + xg4[0]);
      float sf = fsigmoid(g4.y + xg4[1]);
      float tg = ftanh  (g4.z + xg4[2]);
      float so = fsigmoid(g4.w + xg4[3]);
      cst = fmaf(sf, cst, si * tg);
      float h = so * ftanh(cst);
      __hip_atomic_store(hb + (size_t)t * 512 + wg * 16 + tid,
                         __float_as_uint(h),
                         __ATOMIC_RELAXED, __HIP_MEMORY_SCOPE_AGENT);
      if (s + 1 < T_LEN) {
        const int tn = rev ? (t - 1) : (t + 1);
        #pragma unroll
        for (int g = 0; g < 4; ++g)
          xg4[g] = xg[(size_t)tn * 2048 + g * 512 + wg * 16 + tid];
      }
    }
  }

  asm volatile("s_waitcnt vmcnt(0)" : "+v"(A), "+v"(B), "+v"(C) :: "memory");
}

// --------------------------------- pos LSTM (agent-scope history stores) ----
__device__ __forceinline__ void pos_body(
    const float* __restrict__ xg, const float* __restrict__ whh,
    float* __restrict__ hbuf, int rev)
{
  const int tid = threadIdx.x;
  const int p   = tid & 3;
  const int e   = tid >> 2;        // 0..127

  float w[4][32];
  #pragma unroll
  for (int g = 0; g < 4; ++g) {
    const float* row = whh + (size_t)(g * 128 + e) * 128 + 4 * p;
    #pragma unroll
    for (int k = 0; k < 8; ++k) {
      float4 v = *(const float4*)(row + 16 * k);
      w[g][k * 4 + 0] = v.x; w[g][k * 4 + 1] = v.y;
      w[g][k * 4 + 2] = v.z; w[g][k * 4 + 3] = v.w;
    }
  }

  __shared__ __align__(16) float h_lds[2][128];
  unsigned* hb = (unsigned*)hbuf;

  float cst = 0.f;
  float xg4[4] = {0.f, 0.f, 0.f, 0.f};
  if (p == 0) {
    const int t0 = rev ? (T_LEN - 1) : 0;
    #pragma unroll
    for (int g = 0; g < 4; ++g) xg4[g] = xg[(size_t)t0 * 512 + g * 128 + e];
  }
  if (tid < 128) h_lds[0][tid] = 0.f;
  __syncthreads();

  for (int s = 0; s < T_LEN; ++s) {
    const int t   = rev ? (T_LEN - 1 - s) : s;
    const int buf = s & 1;

    float a0 = 0.f, a1 = 0.f, a2 = 0.f, a3 = 0.f;
    #pragma unroll
    for (int k = 0; k < 8; ++k) {
      float4 hv = *(const float4*)&h_lds[buf][16 * k + 4 * p];
      float h4[4] = {hv.x, hv.y, hv.z, hv.w};
      #pragma unroll
      for (int j = 0; j < 4; ++j) {
        a0 = fmaf(w[0][k * 4 + j], h4[j], a0);
        a1 = fmaf(w[1][k * 4 + j], h4[j], a1);
        a2 = fmaf(w[2][k * 4 + j], h4[j], a2);
        a3 = fmaf(w[3][k * 4 + j], h4[j], a3);
      }
    }
    a0 = dpp_add<0xB1>(a0); a1 = dpp_add<0xB1>(a1);
    a2 = dpp_add<0xB1>(a2); a3 = dpp_add<0xB1>(a3);
    a0 = dpp_add<0x4E>(a0); a1 = dpp_add<0x4E>(a1);
    a2 = dpp_add<0x4E>(a2); a3 = dpp_add<0x4E>(a3);

    if (p == 0) {
      float si = fsigmoid(a0 + xg4[0]);
      float sf = fsigmoid(a1 + xg4[1]);
      float tg = ftanh  (a2 + xg4[2]);
      float so = fsigmoid(a3 + xg4[3]);
      cst = fmaf(sf, cst, si * tg);
      float h = so * ftanh(cst);
      h_lds[buf ^ 1][e] = h;                 // next step's operand
      __hip_atomic_store(hb + (size_t)t * 128 + e, __float_as_uint(h),
                         __ATOMIC_RELAXED, __HIP_MEMORY_SCOPE_AGENT);
      if (s + 1 < T_LEN) {
        const int tn = rev ? (t - 1) : (t + 1);
        #pragma unroll
        for (int g = 0; g < 4; ++g)
          xg4[g] = xg[(size_t)tn * 512 + g * 128 + e];
      }
    }
    __syncthreads();
  }
}

// --------------------------------------------- dataflow layer-1 GEMM tile ----
// Readiness order for 64-row tiles: ready step = max(64b+63, 1023-64b).
__device__ const int rtorder[16] = {7,8,6,9,5,10,4,11,3,12,2,13,1,14,0,15};

// Wait until sentinel rows are fully published (agent loads; FF = not ready).
__device__ __forceinline__ void wait_rows(const unsigned* rowF,
                                          const unsigned* rowB, int width) {
  const int tid = threadIdx.x;
  if (tid < width) {
    while (__hip_atomic_load(rowF + tid, __ATOMIC_RELAXED,
                             __HIP_MEMORY_SCOPE_AGENT) == 0xFFFFFFFFu)
      __builtin_amdgcn_s_sleep(8);
    while (__hip_atomic_load(rowB + tid, __ATOMIC_RELAXED,
                             __HIP_MEMORY_SCOPE_AGENT) == 0xFFFFFFFFu)
      __builtin_amdgcn_s_sleep(8);
  }
  __syncthreads();
}

// 64x64 tile of C = [Alo|Ahi] @ W^T + b0 + b1 (K split at ksplit).
// 512 threads launched; tid<256 compute, all hit the barriers.
__device__ __forceinline__ void df_tile(
    const float* __restrict__ Alo, const float* __restrict__ Ahi, int ksplit,
    int K, const float* __restrict__ W,
    const float* __restrict__ b0, const float* __restrict__ b1,
    float* __restrict__ C, int N, int brow, int bcol)
{
  __shared__ __align__(16) float As[16][68];
  __shared__ __align__(16) float Ws[16][68];

  const int tid = threadIdx.x;
  const int tx = tid & 15, ty = (tid >> 4) & 15;
  const int lr = (tid >> 2) & 63;
  const int lk = (tid & 3) << 2;

  float acc[4][4] = {};

  for (int k0 = 0; k0 < K; k0 += 16) {
    float4 av, wv;
    if (tid < 256) {
      const int k = k0 + lk;
      const float* arow = (k < ksplit)
          ? (Alo + (size_t)(brow + lr) * ksplit + k)
          : (Ahi + (size_t)(brow + lr) * ksplit + (k - ksplit));
      av = *(const float4*)arow;
      wv = *(const float4*)(W + (size_t)(bcol + lr) * K + k0 + lk);
    }
    __syncthreads();
    if (tid < 256) {
      As[lk + 0][lr] = av.x; As[lk + 1][lr] = av.y;
      As[lk + 2][lr] = av.z; As[lk + 3][lr] = av.w;
      Ws[lk + 0][lr] = wv.x; Ws[lk + 1][lr] = wv.y;
      Ws[lk + 2][lr] = wv.z; Ws[lk + 3][lr] = wv.w;
    }
    __syncthreads();
    if (tid < 256) {
      #pragma unroll
      for (int kk = 0; kk < 16; ++kk) {
        float4 a = *(const float4*)&As[kk][ty << 2];
        float4 w = *(const float4*)&Ws[kk][tx << 2];
        float a4[4] = {a.x, a.y, a.z, a.w};
        float w4[4] = {w.x, w.y, w.z, w.w};
        #pragma unroll
        for (int i = 0; i < 4; ++i)
          #pragma unroll
          for (int j = 0; j < 4; ++j)
            acc[i][j] = fmaf(a4[i], w4[j], acc[i][j]);
      }
    }
  }

  if (tid < 256) {
    const int nb = bcol + (tx << 2);
    float bias[4];
    #pragma unroll
    for (int j = 0; j < 4; ++j) bias[j] = b0[nb + j] + b1[nb + j];
    #pragma unroll
    for (int i = 0; i < 4; ++i) {
      int m = brow + (ty << 2) + i;
      float4 out;
      out.x = acc[i][0] + bias[0];
      out.y = acc[i][1] + bias[1];
      out.z = acc[i][2] + bias[2];
      out.w = acc[i][3] + bias[3];
      *(float4*)(C + (size_t)m * N + nb) = out;
    }
  }
}

// --------------------------------------------------------- rec (combined) ----
__global__ __launch_bounds__(512, 1) void rec_kernel(
    const float* xg_wf, const float* xg_wb, const float* whh_w,
    float* h_wf, float* h_wb,
    const float* xg_pf, const float* xg_pb, const float* whh_p,
    float* h_pf, float* h_pb,
    const float* w1_ih, const float* w1_b0, const float* w1_b1, float* xg1_w,
    const float* p1_ih, const float* p1_b0, const float* p1_b1, float* xg1_p)
{
  const int b = blockIdx.x;
  if (b < 32) {
    word_body(b, xg_wf, whh_w, h_wf, 0);
  } else if (b < 64) {
    word_body(b - 32, xg_wb, whh_w + 2048 * 512, h_wb, 1);
  } else if (b == 64) {
    pos_body(xg_pf, whh_p, h_pf, 0);
  } else if (b == 65) {
    pos_body(xg_pb, whh_p + 512 * 128, h_pb, 1);
  } else if (b < 194) {
    // word layer-1 dataflow GEMM: 1024 jobs over 128 WGs
    const int g = b - 66;
    for (int j = g; j < 1024; j += 128) {
      const int rti = rtorder[j >> 6];
      const int rem = j & 63;
      const int z = rem >> 5, ct = rem & 31;
      const int brow = rti * 64, bcol = ct * 64;
      wait_rows((const unsigned*)(h_wf + (size_t)(brow + 63) * 512),
                (const unsigned*)(h_wb + (size_t)brow * 512), 512);
      df_tile(h_wf, h_wb, 512, 1024,
              w1_ih + (size_t)z * 2048 * 1024,
              w1_b0 + z * 2048, w1_b1 + z * 2048,
              xg1_w + (size_t)z * 1024 * 2048, 2048, brow, bcol);
    }
  } else {
    // pos layer-1 dataflow GEMM: 256 jobs over 8 WGs
    const int g = b - 194;
    for (int j = g; j < 256; j += 8) {
      const int rti = rtorder[j >> 4];
      const int rem = j & 15;
      const int z = rem >> 3, ct = rem & 7;
      const int brow = rti * 64, bcol = ct * 64;
      wait_rows((const unsigned*)(h_pf + (size_t)(brow + 63) * 128),
                (const unsigned*)(h_pb + (size_t)brow * 128), 128);
      df_tile(h_pf, h_pb, 128, 256,
              p1_ih + (size_t)z * 512 * 256,
              p1_b0 + z * 512, p1_b1 + z * 512,
              xg1_p + (size_t)z * 1024 * 512, 512, brow, bcol);
    }
  }
}

// ------------------------------------------------------------- edge scores ----
__global__ __launch_bounds__(256) void edge_s(
    const float* __restrict__ hwf, const float* __restrict__ hwb,
    const float* __restrict__ hpf, const float* __restrict__ hpb,
    const float* __restrict__ ew, float* s1, float* s2)
{
  const int i = blockIdx.x;
  const int tid = threadIdx.x;
  float a1 = 0.f, a2 = 0.f;
  for (int d = tid; d < 1280; d += 256) {
    float hv;
    if (d < 512)       hv = hwf[i * 512 + d];
    else if (d < 1024) hv = hwb[i * 512 + d - 512];
    else if (d < 1152) hv = hpf[i * 128 + d - 1024];
    else               hv = hpb[i * 128 + d - 1152];
    a1 = fmaf(hv, ew[d], a1);
    a2 = fmaf(hv, ew[1280 + d], a2);
  }
  #pragma unroll
  for (int off = 32; off > 0; off >>= 1) {
    a1 += __shfl_xor(a1, off, 64);
    a2 += __shfl_xor(a2, off, 64);
  }
  __shared__ float r1[4], r2[4];
  const int wid = tid >> 6;
  if ((tid & 63) == 0) { r1[wid] = a1; r2[wid] = a2; }
  __syncthreads();
  if (tid == 0) {
    s1[i] = (r1[0] + r1[1]) + (r1[2] + r1[3]);
    s2[i] = (r2[0] + r2[1]) + (r2[2] + r2[3]);
  }
}

__global__ __launch_bounds__(256) void sfill(
    const float* __restrict__ s1, const float* __restrict__ s2,
    const float* __restrict__ eb, float* __restrict__ out)
{
  int e = blockIdx.x * 256 + threadIdx.x;  // 0 .. 1024*1024-1
  int i = e >> 10, j = e & 1023;
  out[e] = (i == j) ? 0.f : s1[i] + s2[j] + eb[0];
}

// ------------------------------------------------------------------ launch ----
extern "C" void kernel_launch(void* const* d_in, const int* in_sizes, int n_in,
                              void* d_out, int out_size, void* d_ws, size_t ws_size,
                              hipStream_t stream)
{
  const float* words   = (const float*)d_in[0];
  const float* pos     = (const float*)d_in[1];
  const float* w_w0_ih = (const float*)d_in[2];
  const float* w_w0_hh = (const float*)d_in[3];
  const float* w_b0_ih = (const float*)d_in[4];
  const float* w_b0_hh = (const float*)d_in[5];
  const float* w_w1_ih = (const float*)d_in[6];
  const float* w_w1_hh = (const float*)d_in[7];
  const float* w_b1_ih = (const float*)d_in[8];
  const float* w_b1_hh = (const float*)d_in[9];
  const float* p_w0_ih = (const float*)d_in[10];
  const float* p_w0_hh = (const float*)d_in[11];
  const float* p_b0_ih = (const float*)d_in[12];
  const float* p_b0_hh = (const float*)d_in[13];
  const float* p_w1_ih = (const float*)d_in[14];
  const float* p_w1_hh = (const float*)d_in[15];
  const float* p_b1_ih = (const float*)d_in[16];
  const float* p_b1_hh = (const float*)d_in[17];
  const float* edge_w  = (const float*)d_in[18];
  const float* edge_b  = (const float*)d_in[19];

  float* ws = (float*)d_ws;
  float* xg_w  = ws;                       // [2][1024][2048] (layer0, then layer1 in place)
  float* xg_p  = ws + 4194304;             // [2][1024][512]
  float* hw0_f = ws + 5242880;             // [1024][512] each (poisoned)
  float* hw0_b = hw0_f + 524288;
  float* hw1_f = hw0_b + 524288;
  float* hw1_b = hw1_f + 524288;
  float* hp0_f = hw1_b + 524288;           // [1024][128] each (poisoned)
  float* hp0_b = hp0_f + 131072;
  float* hp1_f = hp0_b + 131072;
  float* hp1_b = hp1_f + 131072;
  float* s1    = hp1_b + 131072;
  float* s2    = s1 + 1024;

  // 1. poison hw0_f..hp0_b (word exchange x4 + pos layer-0 sentinels);
  //    every call, since the harness does not re-poison between replays.
  poison_kernel<<<1024, 256, 0, stream>>>((unsigned*)hw0_f, 2359296);

  // 2. layer-0 input projections
  gemm_bt<<<dim3(32, 16, 2), 256, 0, stream>>>(words, w_w0_ih, w_b0_ih, w_b0_hh,
                                               xg_w, 1024, 2048, 512);
  gemm_bt<<<dim3(8, 16, 2), 256, 0, stream>>>(pos, p_w0_ih, p_b0_ih, p_b0_hh,
                                              xg_p, 1024, 512, 128);

  // 3. layer-0 recurrence + dataflow layer-1 projections (202 WGs)
  rec_kernel<<<202, 512, 0, stream>>>(
      xg_w, xg_w + 2097152, w_w0_hh, hw0_f, hw0_b,
      xg_p, xg_p + 524288, p_w0_hh, hp0_f, hp0_b,
      w_w1_ih, w_b1_ih, w_b1_hh, xg_w,
      p_w1_ih, p_b1_ih, p_b1_hh, xg_p);

  // 4. layer-1 recurrence (66 WGs; df branches never dispatched)
  rec_kernel<<<66, 512, 0, stream>>>(
      xg_w, xg_w + 2097152, w_w1_hh, hw1_f, hw1_b,
      xg_p, xg_p + 524288, p_w1_hh, hp1_f, hp1_b,
      w_w1_ih, w_b1_ih, w_b1_hh, xg_w,
      p_w1_ih, p_b1_ih, p_b1_hh, xg_p);

  // 5. edge scores
  edge_s<<<1024, 256, 0, stream>>>(hw1_f, hw1_b, hp1_f, hp1_b, edge_w, s1, s2);
  sfill<<<4096, 256, 0, stream>>>(s1, s2, edge_b, (float*)d_out);
}